// Round 7
// baseline (222.367 us; speedup 1.0000x reference)
//
#include <hip/hip_runtime.h>

typedef unsigned int u32;
typedef __bf16 bf16x8 __attribute__((ext_vector_type(8)));
typedef float f32x4 __attribute__((ext_vector_type(4)));
typedef u32 u32x4 __attribute__((ext_vector_type(4)));

// ---- workspace layout (float offsets) ----
// xs     : 327680   (327680)  f32 [c][n]
// thetaP : 655360   (131072)  bf16 [n][64]   (c 40..63 = 0)
// phiP   : 786432   (131072)  bf16 [m][64]   (c 40..63 = 0)
// gxP    : 917504   (98304)   bf16 [c(48)][m] (rows 40..47 = 0)
// ypart  : 1015808  (1572864) f32 [ck(8)][c(48)][n]
// spart  : 2588672  (32768)   f32 [ck][n]
// yfin   : 2621440  (163840)  f32 [o][n]

static __device__ __forceinline__ u32 f2bf(float f) {
    u32 u = __float_as_uint(f);
    return (u + 0x7fffu + ((u >> 16) & 1u)) >> 16;   // RNE f32->bf16
}

__device__ __forceinline__ void taps_down(int i, int* j, float* w) {
    if (i == 0) {
        j[0]=0; j[1]=0; j[2]=1; j[3]=2;
        w[0]=0.f; w[1]=3.f/7.f; w[2]=3.f/7.f; w[3]=1.f/7.f;
    } else if (i == 31) {
        j[0]=61; j[1]=62; j[2]=63; j[3]=63;
        w[0]=1.f/7.f; w[1]=3.f/7.f; w[2]=3.f/7.f; w[3]=0.f;
    } else {
        j[0]=2*i-1; j[1]=2*i; j[2]=2*i+1; j[3]=2*i+2;
        w[0]=0.125f; w[1]=0.375f; w[2]=0.375f; w[3]=0.125f;
    }
}

// ---------------- fused downsample + projections -------------------------
// grid (16 n-blocks, 11): y<10 -> project o-slice of 4 (downsample fast into
// regs, redundantly per slice — L3-resident); y==10 -> slow->xs + zero-pads.
__global__ __launch_bounds__(256) void k_dp(
        const float* __restrict__ fast, const float* __restrict__ slow,
        const float* __restrict__ gw, const float* __restrict__ gb,
        const float* __restrict__ thw, const float* __restrict__ thb,
        const float* __restrict__ phw, const float* __restrict__ phb,
        unsigned short* __restrict__ gxP, unsigned short* __restrict__ thetaP,
        unsigned short* __restrict__ phiP, float* __restrict__ xs) {
    __shared__ float sW[960];
    __shared__ float sB[12];
    int t = threadIdx.x;
    int by = blockIdx.y;
    int n = blockIdx.x * 256 + t;
    int tt = n >> 10, hh = (n >> 5) & 31, ww = n & 31;
    int jy[4], jx[4]; float wy[4], wx[4];
    taps_down(hh, jy, wy);
    taps_down(ww, jx, wx);

    if (by == 10) {
        // slow -> xs, plus zero-padding of packed operands
#pragma unroll 4
        for (int c = 0; c < 80; ++c) {
            const float* base = slow + ((c * 4 + tt) << 12);
            float acc = 0.f;
#pragma unroll
            for (int a = 0; a < 4; ++a) {
                const float* row = base + (jy[a] << 6);
                acc += wy[a] * (wx[0]*row[jx[0]] + wx[1]*row[jx[1]]
                              + wx[2]*row[jx[2]] + wx[3]*row[jx[3]]);
            }
            xs[c * 4096 + n] = acc;
        }
#pragma unroll
        for (int c = 40; c < 64; ++c) { thetaP[n*64 + c] = 0; phiP[n*64 + c] = 0; }
#pragma unroll
        for (int r = 40; r < 48; ++r) gxP[r * 4096 + n] = 0;
        return;
    }

    int o0 = by * 4;
    for (int i = t; i < 960; i += 256) {
        int mat = i / 320, rem = i % 320;
        int oo = rem / 80, c = rem % 80;
        const float* w = (mat == 0) ? gw : ((mat == 1) ? thw : phw);
        sW[i] = w[(o0 + oo) * 80 + c];
    }
    if (t < 12) {
        int mat = t / 4, oo = t % 4;
        const float* b = (mat == 0) ? gb : ((mat == 1) ? thb : phb);
        sB[t] = b[o0 + oo];
    }
    __syncthreads();

    float x[80];
#pragma unroll 8
    for (int c = 0; c < 80; ++c) {
        const float* base = fast + ((c * 4 + tt) << 12);
        float acc = 0.f;
#pragma unroll
        for (int a = 0; a < 4; ++a) {
            const float* row = base + (jy[a] << 6);
            acc += wy[a] * (wx[0]*row[jx[0]] + wx[1]*row[jx[1]]
                          + wx[2]*row[jx[2]] + wx[3]*row[jx[3]]);
        }
        x[c] = acc;
    }
#pragma unroll
    for (int mat = 0; mat < 3; ++mat) {
#pragma unroll
        for (int oo = 0; oo < 4; ++oo) {
            float acc = sB[mat * 4 + oo];
            const float4* w4 = (const float4*)&sW[mat * 320 + oo * 80];
#pragma unroll
            for (int cq = 0; cq < 20; ++cq) {
                float4 w = w4[cq];
                acc += w.x * x[cq*4] + w.y * x[cq*4+1] + w.z * x[cq*4+2] + w.w * x[cq*4+3];
            }
            int o = o0 + oo;
            if (mat == 0)      gxP[o * 4096 + n]  = (unsigned short)f2bf(acc);
            else if (mat == 1) thetaP[n * 64 + o] = (unsigned short)f2bf(acc);
            else               phiP[n * 64 + o]   = (unsigned short)f2bf(acc);
        }
    }
}

// ---------------- MFMA flash attention (validated R4-R6) -----------------
#define YMM(acc, gfr, bfr) \
    acc = __builtin_amdgcn_mfma_f32_16x16x32_bf16( \
        __builtin_bit_cast(bf16x8, gfr), __builtin_bit_cast(bf16x8, bfr), acc, 0, 0, 0)

__global__ __launch_bounds__(256) void k_attn(
        const unsigned short* __restrict__ thetaP,
        const unsigned short* __restrict__ phiP,
        const unsigned short* __restrict__ gxP,
        float* __restrict__ ypart, float* __restrict__ spart) {
    int lane = threadIdx.x & 63;
    int wv = threadIdx.x >> 6;
    int n0 = blockIdx.x * 64 + wv * 16;
    int ck = blockIdx.y;
    int nl = lane & 15, q = lane >> 4;

    const unsigned short* thp = thetaP + (n0 + nl) * 64 + q * 8;
    u32x4 tb0 = *(const u32x4*)(thp);
    u32x4 tb1 = *(const u32x4*)(thp + 32);

    f32x4 y0 = {0.f,0.f,0.f,0.f}, y1 = y0, y2 = y0;
    float ssum = 0.f;
    int idx0 = ((((q & 1) << 5) + nl) << 2);
    int idx1 = idx0 + 64;

    u32x4 pfA[4], pfB[4], gfA[3], gfB[3];
    int mbase = ck * 512;

#define LOADBLK(P, G, BLK) do {                                              \
        int m0_ = mbase + (BLK) * 32;                                        \
        const unsigned short* pp0_ = phiP + (m0_ + nl) * 64 + q * 8;         \
        const unsigned short* pp1_ = phiP + (m0_ + 16 + nl) * 64 + q * 8;    \
        P[0] = *(const u32x4*)pp0_;  P[1] = *(const u32x4*)(pp0_ + 32);      \
        P[2] = *(const u32x4*)pp1_;  P[3] = *(const u32x4*)(pp1_ + 32);      \
        G[0] = *(const u32x4*)(gxP + (nl) * 4096      + m0_ + q * 8);        \
        G[1] = *(const u32x4*)(gxP + (16 + nl) * 4096 + m0_ + q * 8);        \
        G[2] = *(const u32x4*)(gxP + (32 + nl) * 4096 + m0_ + q * 8);        \
    } while (0)

#define COMPUTE(P, G) do {                                                   \
        u32 p0[2], p1[2];                                                    \
        _Pragma("unroll")                                                    \
        for (int Tm = 0; Tm < 2; ++Tm) {                                     \
            f32x4 f = {0.f,0.f,0.f,0.f};                                     \
            f = __builtin_amdgcn_mfma_f32_16x16x32_bf16(                     \
                __builtin_bit_cast(bf16x8, P[Tm*2+0]),                       \
                __builtin_bit_cast(bf16x8, tb0), f, 0, 0, 0);                \
            f = __builtin_amdgcn_mfma_f32_16x16x32_bf16(                     \
                __builtin_bit_cast(bf16x8, P[Tm*2+1]),                       \
                __builtin_bit_cast(bf16x8, tb1), f, 0, 0, 0);                \
            float e0 = __expf(f[0]), e1 = __expf(f[1]);                      \
            float e2 = __expf(f[2]), e3 = __expf(f[3]);                      \
            ssum += (e0 + e1) + (e2 + e3);                                   \
            p0[Tm] = f2bf(e0) | (f2bf(e1) << 16);                            \
            p1[Tm] = f2bf(e2) | (f2bf(e3) << 16);                            \
        }                                                                    \
        int a0 = __builtin_amdgcn_ds_bpermute(idx0, (int)p0[0]);             \
        int a1 = __builtin_amdgcn_ds_bpermute(idx0, (int)p1[0]);             \
        int a2 = __builtin_amdgcn_ds_bpermute(idx1, (int)p0[0]);             \
        int a3 = __builtin_amdgcn_ds_bpermute(idx1, (int)p1[0]);             \
        int b0 = __builtin_amdgcn_ds_bpermute(idx0, (int)p0[1]);             \
        int b1 = __builtin_amdgcn_ds_bpermute(idx0, (int)p1[1]);             \
        int b2 = __builtin_amdgcn_ds_bpermute(idx1, (int)p0[1]);             \
        int b3 = __builtin_amdgcn_ds_bpermute(idx1, (int)p1[1]);             \
        u32x4 bf_;                                                           \
        bf_[0] = (u32)(q < 2 ? a0 : b0);  bf_[1] = (u32)(q < 2 ? a1 : b1);   \
        bf_[2] = (u32)(q < 2 ? a2 : b2);  bf_[3] = (u32)(q < 2 ? a3 : b3);   \
        YMM(y0, G[0], bf_);  YMM(y1, G[1], bf_);  YMM(y2, G[2], bf_);        \
    } while (0)

    LOADBLK(pfA, gfA, 0);
#pragma unroll 1
    for (int bb = 0; bb < 8; ++bb) {
        LOADBLK(pfB, gfB, bb * 2 + 1);
        COMPUTE(pfA, gfA);
        if (bb < 7) LOADBLK(pfA, gfA, bb * 2 + 2);
        COMPUTE(pfB, gfB);
    }

    ssum += __shfl_xor(ssum, 16);
    ssum += __shfl_xor(ssum, 32);
    if (q == 0) spart[ck * 4096 + n0 + nl] = ssum;

    float* yp = ypart + (size_t)ck * 48 * 4096 + n0 + nl;
#pragma unroll
    for (int r = 0; r < 4; ++r) yp[(q * 4 + r) * 4096] = y0[r];
#pragma unroll
    for (int r = 0; r < 4; ++r) yp[(16 + q * 4 + r) * 4096] = y1[r];
#pragma unroll
    for (int r = 0; r < 4; ++r) yp[(32 + q * 4 + r) * 4096] = y2[r];
}

// ---------------- combine partials -> yfin[o][n] (float4, deep ILP) ------
__global__ __launch_bounds__(256) void k_combine(
        const float* __restrict__ ypart, const float* __restrict__ spart,
        float* __restrict__ yfin) {
    int idx = blockIdx.x * 256 + threadIdx.x;   // 0..40959 (float4 granules)
    int o = idx >> 10;
    int n4 = (idx & 1023) * 4;
    float4 sv[8];
#pragma unroll
    for (int ck = 0; ck < 8; ++ck)
        sv[ck] = *(const float4*)(spart + ck * 4096 + n4);
    float4 yv[8];
#pragma unroll
    for (int ck = 0; ck < 8; ++ck)
        yv[ck] = *(const float4*)(ypart + (size_t)(ck * 48 + o) * 4096 + n4);
    float4 ss = make_float4(0.f,0.f,0.f,0.f), acc = ss;
#pragma unroll
    for (int ck = 0; ck < 8; ++ck) {
        ss.x += sv[ck].x; ss.y += sv[ck].y; ss.z += sv[ck].z; ss.w += sv[ck].w;
        acc.x += yv[ck].x; acc.y += yv[ck].y; acc.z += yv[ck].z; acc.w += yv[ck].w;
    }
    float4 r = make_float4(acc.x/ss.x, acc.y/ss.y, acc.z/ss.z, acc.w/ss.w);
    *(float4*)(yfin + o * 4096 + n4) = r;
}

// ---------------- wz proj + BatchNorm + slow-mult + upsample -------------
__device__ __forceinline__ void taps_up(int i, int* j0, int* j1, float* w0, float* w1) {
    if (i == 0)        { *j0 = 0;        *j1 = 0;          *w0 = 0.f;   *w1 = 1.f;   }
    else if (i == 63)  { *j0 = 31;       *j1 = 31;         *w0 = 1.f;   *w1 = 0.f;   }
    else if (i & 1)    { *j0 = i >> 1;   *j1 = (i>>1) + 1; *w0 = 0.75f; *w1 = 0.25f; }
    else               { *j0 = (i>>1)-1; *j1 = i >> 1;     *w0 = 0.25f; *w1 = 0.75f; }
}

__global__ __launch_bounds__(256) void k_bn_up(
        const float* __restrict__ yfin, const float* __restrict__ wzw,
        const float* __restrict__ wzb, const float* __restrict__ bng,
        const float* __restrict__ bnb, const float* __restrict__ xs,
        float* __restrict__ out) {
    __shared__ float4 wrow4[1024];   // 16 KB
    __shared__ float sred[8];
    int ch = blockIdx.x;
    int t = threadIdx.x;
    float w[40];
#pragma unroll
    for (int o = 0; o < 40; ++o) w[o] = wzw[ch * 40 + o];
    float bias = wzb[ch];
    float s1 = 0.f, s2 = 0.f;
#pragma unroll 1
    for (int k = 0; k < 4; ++k) {
        int i = k * 256 + t;
        float4 yv[40];
#pragma unroll
        for (int o = 0; o < 40; ++o)
            yv[o] = *(const float4*)(yfin + o * 4096 + i * 4);
        float4 a = make_float4(bias, bias, bias, bias);
#pragma unroll
        for (int o = 0; o < 40; ++o) {
            a.x += w[o]*yv[o].x; a.y += w[o]*yv[o].y;
            a.z += w[o]*yv[o].z; a.w += w[o]*yv[o].w;
        }
        wrow4[i] = a;
        s1 += a.x + a.y + a.z + a.w;
        s2 += a.x*a.x + a.y*a.y + a.z*a.z + a.w*a.w;
    }
#pragma unroll
    for (int off = 32; off > 0; off >>= 1) {
        s1 += __shfl_down(s1, off);
        s2 += __shfl_down(s2, off);
    }
    int wid = t >> 6;
    if ((t & 63) == 0) { sred[wid] = s1; sred[4 + wid] = s2; }
    __syncthreads();
    float mean = (sred[0] + sred[1] + sred[2] + sred[3]) * (1.f / 4096.f);
    float var  = (sred[4] + sred[5] + sred[6] + sred[7]) * (1.f / 4096.f) - mean * mean;
    float inv = rsqrtf(var + 1e-5f);
    float sc = bng[ch] * inv;
    float sh = bnb[ch] - mean * sc;
#pragma unroll
    for (int k = 0; k < 4; ++k) {
        int i = k * 256 + t;
        float4 a = wrow4[i];
        float4 xv = *(const float4*)(xs + ch * 4096 + i * 4);
        a.x = (a.x*sc + sh)*xv.x; a.y = (a.y*sc + sh)*xv.y;
        a.z = (a.z*sc + sh)*xv.z; a.w = (a.w*sc + sh)*xv.w;
        wrow4[i] = a;
    }
    __syncthreads();
    const float* zs = (const float*)wrow4;
    int chbase = ch << 14;
#pragma unroll 4
    for (int k = 0; k < 64; ++k) {
        int p = k * 256 + t;          // 0..16383
        int tt = p >> 12, yy = (p >> 6) & 63, xx = p & 63;
        int jy0, jy1, jx0, jx1; float wy0, wy1, wx0, wx1;
        taps_up(yy, &jy0, &jy1, &wy0, &wy1);
        taps_up(xx, &jx0, &jx1, &wx0, &wx1);
        const float* pl = zs + tt * 1024;
        float r0 = wx0*pl[jy0*32 + jx0] + wx1*pl[jy0*32 + jx1];
        float r1 = wx0*pl[jy1*32 + jx0] + wx1*pl[jy1*32 + jx1];
        out[chbase + p] = wy0*r0 + wy1*r1;
    }
}

extern "C" void kernel_launch(void* const* d_in, const int* in_sizes, int n_in,
                              void* d_out, int out_size, void* d_ws, size_t ws_size,
                              hipStream_t stream) {
    const float* fast = (const float*)d_in[0];
    const float* slow = (const float*)d_in[1];
    const float* g_w  = (const float*)d_in[2];
    const float* g_b  = (const float*)d_in[3];
    const float* th_w = (const float*)d_in[4];
    const float* th_b = (const float*)d_in[5];
    const float* ph_w = (const float*)d_in[6];
    const float* ph_b = (const float*)d_in[7];
    const float* wz_w = (const float*)d_in[8];
    const float* wz_b = (const float*)d_in[9];
    const float* bn_g = (const float*)d_in[10];
    const float* bn_b = (const float*)d_in[11];
    float* out = (float*)d_out;
    float* ws  = (float*)d_ws;

    float* xs = ws + 327680;
    unsigned short* thetaP = (unsigned short*)(ws + 655360);
    unsigned short* phiP   = (unsigned short*)(ws + 786432);
    unsigned short* gxP    = (unsigned short*)(ws + 917504);
    float* ypart = ws + 1015808;
    float* spart = ws + 2588672;
    float* yfin  = ws + 2621440;

    k_dp<<<dim3(16, 11), 256, 0, stream>>>(fast, slow, g_w, g_b, th_w, th_b,
                                           ph_w, ph_b, gxP, thetaP, phiP, xs);
    k_attn<<<dim3(64, 8), 256, 0, stream>>>(thetaP, phiP, gxP, ypart, spart);
    k_combine<<<160, 256, 0, stream>>>(ypart, spart, yfin);
    k_bn_up<<<80, 256, 0, stream>>>(yfin, wz_w, wz_b, bn_g, bn_b, xs, out);
}

// Round 8
// 144.454 us; speedup vs baseline: 1.5394x; 1.5394x over previous
//
#include <hip/hip_runtime.h>

typedef unsigned int u32;
typedef __bf16 bf16x8 __attribute__((ext_vector_type(8)));
typedef float f32x4 __attribute__((ext_vector_type(4)));
typedef u32 u32x4 __attribute__((ext_vector_type(4)));

// ---- workspace layout (float offsets) ----
// xf     : 0        (327680)  f32 [c][n]
// xs     : 327680   (327680)  f32 [c][n]
// thetaP : 655360   (131072)  bf16 [n][64]   (c 40..63 = 0)
// phiP   : 786432   (131072)  bf16 [m][64]   (c 40..63 = 0)
// gxP    : 917504   (98304)   bf16 [c(48)][m] (rows 40..47 = 0)
// ypart  : 1015808  (1572864) f32 [ck(8)][c(48)][n]
// spart  : 2588672  (32768)   f32 [ck][n]
// yfin   : 2621440  (163840)  f32 [o][n]

static __device__ __forceinline__ u32 f2bf(float f) {
    u32 u = __float_as_uint(f);
    return (u + 0x7fffu + ((u >> 16) & 1u)) >> 16;   // RNE f32->bf16
}

__device__ __forceinline__ void taps_down(int i, int* j, float* w) {
    if (i == 0) {
        j[0]=0; j[1]=0; j[2]=1; j[3]=2;
        w[0]=0.f; w[1]=3.f/7.f; w[2]=3.f/7.f; w[3]=1.f/7.f;
    } else if (i == 31) {
        j[0]=61; j[1]=62; j[2]=63; j[3]=63;
        w[0]=1.f/7.f; w[1]=3.f/7.f; w[2]=3.f/7.f; w[3]=0.f;
    } else {
        j[0]=2*i-1; j[1]=2*i; j[2]=2*i+1; j[3]=2*i+2;
        w[0]=0.125f; w[1]=0.375f; w[2]=0.375f; w[3]=0.125f;
    }
}

// ---------------- downsample 64 -> 32 (2560 WGs, proven) -----------------
__global__ __launch_bounds__(256) void k_down(
        const float* __restrict__ fast, const float* __restrict__ slow,
        float* __restrict__ xf, float* __restrict__ xs) {
    int idx = blockIdx.x * 256 + threadIdx.x;   // 0 .. 655359
    int which = idx >= 327680;
    int rem = which ? idx - 327680 : idx;
    const float* src = which ? slow : fast;
    float* dst = which ? xs : xf;
    int c = rem >> 12;
    int n = rem & 4095;
    int tt = n >> 10, hh = (n >> 5) & 31, ww = n & 31;
    int jy[4], jx[4]; float wy[4], wx[4];
    taps_down(hh, jy, wy);
    taps_down(ww, jx, wx);
    const float* base = src + ((c * 4 + tt) << 12);
    float acc = 0.f;
#pragma unroll
    for (int a = 0; a < 4; ++a) {
        const float* row = base + (jy[a] << 6);
        acc += wy[a] * (wx[0]*row[jx[0]] + wx[1]*row[jx[1]]
                      + wx[2]*row[jx[2]] + wx[3]*row[jx[3]]);
    }
    dst[rem] = acc;
}

// ---------------- projections -> packed bf16 operand layouts -------------
// grid (16 n-blocks, 20 o-slices of 2) = 320 WGs (R6 had 160 -> WG-starved)
__global__ __launch_bounds__(256) void k_proj(
        const float* __restrict__ xf,
        const float* __restrict__ gw, const float* __restrict__ gb,
        const float* __restrict__ thw, const float* __restrict__ thb,
        const float* __restrict__ phw, const float* __restrict__ phb,
        unsigned short* __restrict__ gxP, unsigned short* __restrict__ thetaP,
        unsigned short* __restrict__ phiP) {
    __shared__ float sW[480];   // mat*160 + oo*80 + c
    __shared__ float sB[6];
    int t = threadIdx.x;
    int o0 = blockIdx.y * 2;
    for (int i = t; i < 480; i += 256) {
        int mat = i / 160, rem = i % 160;
        int oo = rem / 80, c = rem % 80;
        const float* w = (mat == 0) ? gw : ((mat == 1) ? thw : phw);
        sW[i] = w[(o0 + oo) * 80 + c];
    }
    if (t < 6) {
        int mat = t / 2, oo = t % 2;
        const float* b = (mat == 0) ? gb : ((mat == 1) ? thb : phb);
        sB[t] = b[o0 + oo];
    }
    __syncthreads();
    int n = blockIdx.x * 256 + t;
    if (blockIdx.y == 0) {
#pragma unroll
        for (int c = 40; c < 64; ++c) { thetaP[n*64 + c] = 0; phiP[n*64 + c] = 0; }
#pragma unroll
        for (int r = 40; r < 48; ++r) gxP[r * 4096 + n] = 0;
    }
    float x[80];
#pragma unroll
    for (int c = 0; c < 80; ++c) x[c] = xf[c * 4096 + n];
#pragma unroll
    for (int mat = 0; mat < 3; ++mat) {
#pragma unroll
        for (int oo = 0; oo < 2; ++oo) {
            float acc = sB[mat * 2 + oo];
            const float4* w4 = (const float4*)&sW[mat * 160 + oo * 80];
#pragma unroll
            for (int cq = 0; cq < 20; ++cq) {
                float4 w = w4[cq];
                acc += w.x * x[cq*4] + w.y * x[cq*4+1] + w.z * x[cq*4+2] + w.w * x[cq*4+3];
            }
            int o = o0 + oo;
            if (mat == 0)      gxP[o * 4096 + n]  = (unsigned short)f2bf(acc);
            else if (mat == 1) thetaP[n * 64 + o] = (unsigned short)f2bf(acc);
            else               phiP[n * 64 + o]   = (unsigned short)f2bf(acc);
        }
    }
}

// ---------------- MFMA flash attention (validated R4-R6) -----------------
#define YMM(acc, gfr, bfr) \
    acc = __builtin_amdgcn_mfma_f32_16x16x32_bf16( \
        __builtin_bit_cast(bf16x8, gfr), __builtin_bit_cast(bf16x8, bfr), acc, 0, 0, 0)

__global__ __launch_bounds__(256) void k_attn(
        const unsigned short* __restrict__ thetaP,
        const unsigned short* __restrict__ phiP,
        const unsigned short* __restrict__ gxP,
        float* __restrict__ ypart, float* __restrict__ spart) {
    int lane = threadIdx.x & 63;
    int wv = threadIdx.x >> 6;
    int n0 = blockIdx.x * 64 + wv * 16;
    int ck = blockIdx.y;
    int nl = lane & 15, q = lane >> 4;

    const unsigned short* thp = thetaP + (n0 + nl) * 64 + q * 8;
    u32x4 tb0 = *(const u32x4*)(thp);
    u32x4 tb1 = *(const u32x4*)(thp + 32);

    f32x4 y0 = {0.f,0.f,0.f,0.f}, y1 = y0, y2 = y0;
    float ssum = 0.f;
    int idx0 = ((((q & 1) << 5) + nl) << 2);
    int idx1 = idx0 + 64;

    u32x4 pfA[4], pfB[4], gfA[3], gfB[3];
    int mbase = ck * 512;

#define LOADBLK(P, G, BLK) do {                                              \
        int m0_ = mbase + (BLK) * 32;                                        \
        const unsigned short* pp0_ = phiP + (m0_ + nl) * 64 + q * 8;         \
        const unsigned short* pp1_ = phiP + (m0_ + 16 + nl) * 64 + q * 8;    \
        P[0] = *(const u32x4*)pp0_;  P[1] = *(const u32x4*)(pp0_ + 32);      \
        P[2] = *(const u32x4*)pp1_;  P[3] = *(const u32x4*)(pp1_ + 32);      \
        G[0] = *(const u32x4*)(gxP + (nl) * 4096      + m0_ + q * 8);        \
        G[1] = *(const u32x4*)(gxP + (16 + nl) * 4096 + m0_ + q * 8);        \
        G[2] = *(const u32x4*)(gxP + (32 + nl) * 4096 + m0_ + q * 8);        \
    } while (0)

#define COMPUTE(P, G) do {                                                   \
        u32 p0[2], p1[2];                                                    \
        _Pragma("unroll")                                                    \
        for (int Tm = 0; Tm < 2; ++Tm) {                                     \
            f32x4 f = {0.f,0.f,0.f,0.f};                                     \
            f = __builtin_amdgcn_mfma_f32_16x16x32_bf16(                     \
                __builtin_bit_cast(bf16x8, P[Tm*2+0]),                       \
                __builtin_bit_cast(bf16x8, tb0), f, 0, 0, 0);                \
            f = __builtin_amdgcn_mfma_f32_16x16x32_bf16(                     \
                __builtin_bit_cast(bf16x8, P[Tm*2+1]),                       \
                __builtin_bit_cast(bf16x8, tb1), f, 0, 0, 0);                \
            float e0 = __expf(f[0]), e1 = __expf(f[1]);                      \
            float e2 = __expf(f[2]), e3 = __expf(f[3]);                      \
            ssum += (e0 + e1) + (e2 + e3);                                   \
            p0[Tm] = f2bf(e0) | (f2bf(e1) << 16);                            \
            p1[Tm] = f2bf(e2) | (f2bf(e3) << 16);                            \
        }                                                                    \
        int a0 = __builtin_amdgcn_ds_bpermute(idx0, (int)p0[0]);             \
        int a1 = __builtin_amdgcn_ds_bpermute(idx0, (int)p1[0]);             \
        int a2 = __builtin_amdgcn_ds_bpermute(idx1, (int)p0[0]);             \
        int a3 = __builtin_amdgcn_ds_bpermute(idx1, (int)p1[0]);             \
        int b0 = __builtin_amdgcn_ds_bpermute(idx0, (int)p0[1]);             \
        int b1 = __builtin_amdgcn_ds_bpermute(idx0, (int)p1[1]);             \
        int b2 = __builtin_amdgcn_ds_bpermute(idx1, (int)p0[1]);             \
        int b3 = __builtin_amdgcn_ds_bpermute(idx1, (int)p1[1]);             \
        u32x4 bf_;                                                           \
        bf_[0] = (u32)(q < 2 ? a0 : b0);  bf_[1] = (u32)(q < 2 ? a1 : b1);   \
        bf_[2] = (u32)(q < 2 ? a2 : b2);  bf_[3] = (u32)(q < 2 ? a3 : b3);   \
        YMM(y0, G[0], bf_);  YMM(y1, G[1], bf_);  YMM(y2, G[2], bf_);        \
    } while (0)

    LOADBLK(pfA, gfA, 0);
#pragma unroll 1
    for (int bb = 0; bb < 8; ++bb) {
        LOADBLK(pfB, gfB, bb * 2 + 1);
        COMPUTE(pfA, gfA);
        if (bb < 7) LOADBLK(pfA, gfA, bb * 2 + 2);
        COMPUTE(pfB, gfB);
    }

    ssum += __shfl_xor(ssum, 16);
    ssum += __shfl_xor(ssum, 32);
    if (q == 0) spart[ck * 4096 + n0 + nl] = ssum;

    float* yp = ypart + (size_t)ck * 48 * 4096 + n0 + nl;
#pragma unroll
    for (int r = 0; r < 4; ++r) yp[(q * 4 + r) * 4096] = y0[r];
#pragma unroll
    for (int r = 0; r < 4; ++r) yp[(16 + q * 4 + r) * 4096] = y1[r];
#pragma unroll
    for (int r = 0; r < 4; ++r) yp[(32 + q * 4 + r) * 4096] = y2[r];
}

// ---------------- combine partials -> yfin[o][n] (float4, deep ILP) ------
__global__ __launch_bounds__(256) void k_combine(
        const float* __restrict__ ypart, const float* __restrict__ spart,
        float* __restrict__ yfin) {
    int idx = blockIdx.x * 256 + threadIdx.x;   // 0..40959 (float4 granules)
    int o = idx >> 10;
    int n4 = (idx & 1023) * 4;
    float4 sv[8];
#pragma unroll
    for (int ck = 0; ck < 8; ++ck)
        sv[ck] = *(const float4*)(spart + ck * 4096 + n4);
    float4 yv[8];
#pragma unroll
    for (int ck = 0; ck < 8; ++ck)
        yv[ck] = *(const float4*)(ypart + (size_t)(ck * 48 + o) * 4096 + n4);
    float4 ss = make_float4(0.f,0.f,0.f,0.f), acc = ss;
#pragma unroll
    for (int ck = 0; ck < 8; ++ck) {
        ss.x += sv[ck].x; ss.y += sv[ck].y; ss.z += sv[ck].z; ss.w += sv[ck].w;
        acc.x += yv[ck].x; acc.y += yv[ck].y; acc.z += yv[ck].z; acc.w += yv[ck].w;
    }
    float4 r = make_float4(acc.x/ss.x, acc.y/ss.y, acc.z/ss.z, acc.w/ss.w);
    *(float4*)(yfin + o * 4096 + n4) = r;
}

// ---------------- wz proj + BatchNorm + slow-mult + upsample -------------
__device__ __forceinline__ void taps_up(int i, int* j0, int* j1, float* w0, float* w1) {
    if (i == 0)        { *j0 = 0;        *j1 = 0;          *w0 = 0.f;   *w1 = 1.f;   }
    else if (i == 63)  { *j0 = 31;       *j1 = 31;         *w0 = 1.f;   *w1 = 0.f;   }
    else if (i & 1)    { *j0 = i >> 1;   *j1 = (i>>1) + 1; *w0 = 0.75f; *w1 = 0.25f; }
    else               { *j0 = (i>>1)-1; *j1 = i >> 1;     *w0 = 0.25f; *w1 = 0.75f; }
}

__global__ __launch_bounds__(256) void k_bn_up(
        const float* __restrict__ yfin, const float* __restrict__ wzw,
        const float* __restrict__ wzb, const float* __restrict__ bng,
        const float* __restrict__ bnb, const float* __restrict__ xs,
        float* __restrict__ out) {
    __shared__ float4 wrow4[1024];   // 16 KB
    __shared__ float sred[8];
    int ch = blockIdx.x;
    int t = threadIdx.x;
    float w[40];
#pragma unroll
    for (int o = 0; o < 40; ++o) w[o] = wzw[ch * 40 + o];
    float bias = wzb[ch];
    float s1 = 0.f, s2 = 0.f;
#pragma unroll 1
    for (int k = 0; k < 4; ++k) {
        int i = k * 256 + t;
        float4 yv[40];
#pragma unroll
        for (int o = 0; o < 40; ++o)
            yv[o] = *(const float4*)(yfin + o * 4096 + i * 4);
        float4 a = make_float4(bias, bias, bias, bias);
#pragma unroll
        for (int o = 0; o < 40; ++o) {
            a.x += w[o]*yv[o].x; a.y += w[o]*yv[o].y;
            a.z += w[o]*yv[o].z; a.w += w[o]*yv[o].w;
        }
        wrow4[i] = a;
        s1 += a.x + a.y + a.z + a.w;
        s2 += a.x*a.x + a.y*a.y + a.z*a.z + a.w*a.w;
    }
#pragma unroll
    for (int off = 32; off > 0; off >>= 1) {
        s1 += __shfl_down(s1, off);
        s2 += __shfl_down(s2, off);
    }
    int wid = t >> 6;
    if ((t & 63) == 0) { sred[wid] = s1; sred[4 + wid] = s2; }
    __syncthreads();
    float mean = (sred[0] + sred[1] + sred[2] + sred[3]) * (1.f / 4096.f);
    float var  = (sred[4] + sred[5] + sred[6] + sred[7]) * (1.f / 4096.f) - mean * mean;
    float inv = rsqrtf(var + 1e-5f);
    float sc = bng[ch] * inv;
    float sh = bnb[ch] - mean * sc;
#pragma unroll
    for (int k = 0; k < 4; ++k) {
        int i = k * 256 + t;
        float4 a = wrow4[i];
        float4 xv = *(const float4*)(xs + ch * 4096 + i * 4);
        a.x = (a.x*sc + sh)*xv.x; a.y = (a.y*sc + sh)*xv.y;
        a.z = (a.z*sc + sh)*xv.z; a.w = (a.w*sc + sh)*xv.w;
        wrow4[i] = a;
    }
    __syncthreads();
    const float* zs = (const float*)wrow4;
    int chbase = ch << 14;
#pragma unroll 4
    for (int k = 0; k < 64; ++k) {
        int p = k * 256 + t;          // 0..16383
        int tt = p >> 12, yy = (p >> 6) & 63, xx = p & 63;
        int jy0, jy1, jx0, jx1; float wy0, wy1, wx0, wx1;
        taps_up(yy, &jy0, &jy1, &wy0, &wy1);
        taps_up(xx, &jx0, &jx1, &wx0, &wx1);
        const float* pl = zs + tt * 1024;
        float r0 = wx0*pl[jy0*32 + jx0] + wx1*pl[jy0*32 + jx1];
        float r1 = wx0*pl[jy1*32 + jx0] + wx1*pl[jy1*32 + jx1];
        out[chbase + p] = wy0*r0 + wy1*r1;
    }
}

extern "C" void kernel_launch(void* const* d_in, const int* in_sizes, int n_in,
                              void* d_out, int out_size, void* d_ws, size_t ws_size,
                              hipStream_t stream) {
    const float* fast = (const float*)d_in[0];
    const float* slow = (const float*)d_in[1];
    const float* g_w  = (const float*)d_in[2];
    const float* g_b  = (const float*)d_in[3];
    const float* th_w = (const float*)d_in[4];
    const float* th_b = (const float*)d_in[5];
    const float* ph_w = (const float*)d_in[6];
    const float* ph_b = (const float*)d_in[7];
    const float* wz_w = (const float*)d_in[8];
    const float* wz_b = (const float*)d_in[9];
    const float* bn_g = (const float*)d_in[10];
    const float* bn_b = (const float*)d_in[11];
    float* out = (float*)d_out;
    float* ws  = (float*)d_ws;

    float* xf = ws;
    float* xs = ws + 327680;
    unsigned short* thetaP = (unsigned short*)(ws + 655360);
    unsigned short* phiP   = (unsigned short*)(ws + 786432);
    unsigned short* gxP    = (unsigned short*)(ws + 917504);
    float* ypart = ws + 1015808;
    float* spart = ws + 2588672;
    float* yfin  = ws + 2621440;

    k_down<<<2560, 256, 0, stream>>>(fast, slow, xf, xs);
    k_proj<<<dim3(16, 20), 256, 0, stream>>>(xf, g_w, g_b, th_w, th_b, ph_w, ph_b,
                                             gxP, thetaP, phiP);
    k_attn<<<dim3(64, 8), 256, 0, stream>>>(thetaP, phiP, gxP, ypart, spart);
    k_combine<<<160, 256, 0, stream>>>(ypart, spart, yfin);
    k_bn_up<<<80, 256, 0, stream>>>(yfin, wz_w, wz_b, bn_g, bn_b, xs, out);
}

// Round 9
// 140.595 us; speedup vs baseline: 1.5816x; 1.0274x over previous
//
#include <hip/hip_runtime.h>

typedef unsigned int u32;
typedef __bf16 bf16x8 __attribute__((ext_vector_type(8)));
typedef float f32x4 __attribute__((ext_vector_type(4)));
typedef u32 u32x4 __attribute__((ext_vector_type(4)));

// ---- workspace layout (float offsets) ----
// xf     : 0        (327680)  f32 [c][n]
// xs     : 327680   (327680)  f32 [c][n]
// thetaP : 655360   (131072)  bf16 [n][64]   (c 40..63 = 0)
// phiP   : 786432   (131072)  bf16 [m][64]   (c 40..63 = 0)
// gxP    : 917504   (98304)   bf16 [c(48)][m] (rows 40..47 = 0)
// yfin   : 1015808  (163840)  f32 [o][n]

static __device__ __forceinline__ u32 f2bf(float f) {
    u32 u = __float_as_uint(f);
    return (u + 0x7fffu + ((u >> 16) & 1u)) >> 16;   // RNE f32->bf16
}

__device__ __forceinline__ void taps_down(int i, int* j, float* w) {
    if (i == 0) {
        j[0]=0; j[1]=0; j[2]=1; j[3]=2;
        w[0]=0.f; w[1]=3.f/7.f; w[2]=3.f/7.f; w[3]=1.f/7.f;
    } else if (i == 31) {
        j[0]=61; j[1]=62; j[2]=63; j[3]=63;
        w[0]=1.f/7.f; w[1]=3.f/7.f; w[2]=3.f/7.f; w[3]=0.f;
    } else {
        j[0]=2*i-1; j[1]=2*i; j[2]=2*i+1; j[3]=2*i+2;
        w[0]=0.125f; w[1]=0.375f; w[2]=0.375f; w[3]=0.125f;
    }
}

// ---------------- downsample 64 -> 32 (2560 WGs, proven) -----------------
__global__ __launch_bounds__(256) void k_down(
        const float* __restrict__ fast, const float* __restrict__ slow,
        float* __restrict__ xf, float* __restrict__ xs) {
    int idx = blockIdx.x * 256 + threadIdx.x;   // 0 .. 655359
    int which = idx >= 327680;
    int rem = which ? idx - 327680 : idx;
    const float* src = which ? slow : fast;
    float* dst = which ? xs : xf;
    int c = rem >> 12;
    int n = rem & 4095;
    int tt = n >> 10, hh = (n >> 5) & 31, ww = n & 31;
    int jy[4], jx[4]; float wy[4], wx[4];
    taps_down(hh, jy, wy);
    taps_down(ww, jx, wx);
    const float* base = src + ((c * 4 + tt) << 12);
    float acc = 0.f;
#pragma unroll
    for (int a = 0; a < 4; ++a) {
        const float* row = base + (jy[a] << 6);
        acc += wy[a] * (wx[0]*row[jx[0]] + wx[1]*row[jx[1]]
                      + wx[2]*row[jx[2]] + wx[3]*row[jx[3]]);
    }
    dst[rem] = acc;
}

// ---------------- projections -> packed bf16 operand layouts -------------
// grid (16 n-blocks, 20 o-slices of 2) = 320 WGs (validated R8)
__global__ __launch_bounds__(256) void k_proj(
        const float* __restrict__ xf,
        const float* __restrict__ gw, const float* __restrict__ gb,
        const float* __restrict__ thw, const float* __restrict__ thb,
        const float* __restrict__ phw, const float* __restrict__ phb,
        unsigned short* __restrict__ gxP, unsigned short* __restrict__ thetaP,
        unsigned short* __restrict__ phiP) {
    __shared__ float sW[480];   // mat*160 + oo*80 + c
    __shared__ float sB[6];
    int t = threadIdx.x;
    int o0 = blockIdx.y * 2;
    for (int i = t; i < 480; i += 256) {
        int mat = i / 160, rem = i % 160;
        int oo = rem / 80, c = rem % 80;
        const float* w = (mat == 0) ? gw : ((mat == 1) ? thw : phw);
        sW[i] = w[(o0 + oo) * 80 + c];
    }
    if (t < 6) {
        int mat = t / 2, oo = t % 2;
        const float* b = (mat == 0) ? gb : ((mat == 1) ? thb : phb);
        sB[t] = b[o0 + oo];
    }
    __syncthreads();
    int n = blockIdx.x * 256 + t;
    if (blockIdx.y == 0) {
#pragma unroll
        for (int c = 40; c < 64; ++c) { thetaP[n*64 + c] = 0; phiP[n*64 + c] = 0; }
#pragma unroll
        for (int r = 40; r < 48; ++r) gxP[r * 4096 + n] = 0;
    }
    float x[80];
#pragma unroll
    for (int c = 0; c < 80; ++c) x[c] = xf[c * 4096 + n];
#pragma unroll
    for (int mat = 0; mat < 3; ++mat) {
#pragma unroll
        for (int oo = 0; oo < 2; ++oo) {
            float acc = sB[mat * 2 + oo];
            const float4* w4 = (const float4*)&sW[mat * 160 + oo * 80];
#pragma unroll
            for (int cq = 0; cq < 20; ++cq) {
                float4 w = w4[cq];
                acc += w.x * x[cq*4] + w.y * x[cq*4+1] + w.z * x[cq*4+2] + w.w * x[cq*4+3];
            }
            int o = o0 + oo;
            if (mat == 0)      gxP[o * 4096 + n]  = (unsigned short)f2bf(acc);
            else if (mat == 1) thetaP[n * 64 + o] = (unsigned short)f2bf(acc);
            else               phiP[n * 64 + o]   = (unsigned short)f2bf(acc);
        }
    }
}

// ---------------- MFMA flash attention, single-pass ----------------------
// grid 256: WG owns one 16-n tile; 4 waves own m-quarters (1024 m each);
// intra-WG LDS reduction replaces the R8 cross-WG ypart/combine pass.
#define YMM(acc, gfr, bfr) \
    acc = __builtin_amdgcn_mfma_f32_16x16x32_bf16( \
        __builtin_bit_cast(bf16x8, gfr), __builtin_bit_cast(bf16x8, bfr), acc, 0, 0, 0)

__global__ __launch_bounds__(256) void k_attn(
        const unsigned short* __restrict__ thetaP,
        const unsigned short* __restrict__ phiP,
        const unsigned short* __restrict__ gxP,
        float* __restrict__ yfin) {
    __shared__ float yred[4][48][16];   // 12 KB
    __shared__ float sred[4][16];
    int t = threadIdx.x;
    int lane = t & 63;
    int wv = t >> 6;
    int n0 = blockIdx.x * 16;
    int nl = lane & 15, q = lane >> 4;

    const unsigned short* thp = thetaP + (n0 + nl) * 64 + q * 8;
    u32x4 tb0 = *(const u32x4*)(thp);
    u32x4 tb1 = *(const u32x4*)(thp + 32);

    f32x4 y0 = {0.f,0.f,0.f,0.f}, y1 = y0, y2 = y0;
    float ssum = 0.f;
    int idx0 = ((((q & 1) << 5) + nl) << 2);
    int idx1 = idx0 + 64;

    u32x4 pfA[4], pfB[4], gfA[3], gfB[3];
    int mbase = wv * 1024;   // wave's m-quarter

#define LOADBLK(P, G, BLK) do {                                              \
        int m0_ = mbase + (BLK) * 32;                                        \
        const unsigned short* pp0_ = phiP + (m0_ + nl) * 64 + q * 8;         \
        const unsigned short* pp1_ = phiP + (m0_ + 16 + nl) * 64 + q * 8;    \
        P[0] = *(const u32x4*)pp0_;  P[1] = *(const u32x4*)(pp0_ + 32);      \
        P[2] = *(const u32x4*)pp1_;  P[3] = *(const u32x4*)(pp1_ + 32);      \
        G[0] = *(const u32x4*)(gxP + (nl) * 4096      + m0_ + q * 8);        \
        G[1] = *(const u32x4*)(gxP + (16 + nl) * 4096 + m0_ + q * 8);        \
        G[2] = *(const u32x4*)(gxP + (32 + nl) * 4096 + m0_ + q * 8);        \
    } while (0)

#define COMPUTE(P, G) do {                                                   \
        u32 p0[2], p1[2];                                                    \
        _Pragma("unroll")                                                    \
        for (int Tm = 0; Tm < 2; ++Tm) {                                     \
            f32x4 f = {0.f,0.f,0.f,0.f};                                     \
            f = __builtin_amdgcn_mfma_f32_16x16x32_bf16(                     \
                __builtin_bit_cast(bf16x8, P[Tm*2+0]),                       \
                __builtin_bit_cast(bf16x8, tb0), f, 0, 0, 0);                \
            f = __builtin_amdgcn_mfma_f32_16x16x32_bf16(                     \
                __builtin_bit_cast(bf16x8, P[Tm*2+1]),                       \
                __builtin_bit_cast(bf16x8, tb1), f, 0, 0, 0);                \
            float e0 = __expf(f[0]), e1 = __expf(f[1]);                      \
            float e2 = __expf(f[2]), e3 = __expf(f[3]);                      \
            ssum += (e0 + e1) + (e2 + e3);                                   \
            p0[Tm] = f2bf(e0) | (f2bf(e1) << 16);                            \
            p1[Tm] = f2bf(e2) | (f2bf(e3) << 16);                            \
        }                                                                    \
        int a0 = __builtin_amdgcn_ds_bpermute(idx0, (int)p0[0]);             \
        int a1 = __builtin_amdgcn_ds_bpermute(idx0, (int)p1[0]);             \
        int a2 = __builtin_amdgcn_ds_bpermute(idx1, (int)p0[0]);             \
        int a3 = __builtin_amdgcn_ds_bpermute(idx1, (int)p1[0]);             \
        int b0 = __builtin_amdgcn_ds_bpermute(idx0, (int)p0[1]);             \
        int b1 = __builtin_amdgcn_ds_bpermute(idx0, (int)p1[1]);             \
        int b2 = __builtin_amdgcn_ds_bpermute(idx1, (int)p0[1]);             \
        int b3 = __builtin_amdgcn_ds_bpermute(idx1, (int)p1[1]);             \
        u32x4 bf_;                                                           \
        bf_[0] = (u32)(q < 2 ? a0 : b0);  bf_[1] = (u32)(q < 2 ? a1 : b1);   \
        bf_[2] = (u32)(q < 2 ? a2 : b2);  bf_[3] = (u32)(q < 2 ? a3 : b3);   \
        YMM(y0, G[0], bf_);  YMM(y1, G[1], bf_);  YMM(y2, G[2], bf_);        \
    } while (0)

    LOADBLK(pfA, gfA, 0);
#pragma unroll 1
    for (int bb = 0; bb < 16; ++bb) {   // 32 blocks of 32 m, double-buffered
        LOADBLK(pfB, gfB, bb * 2 + 1);
        COMPUTE(pfA, gfA);
        if (bb < 15) LOADBLK(pfA, gfA, bb * 2 + 2);
        COMPUTE(pfB, gfB);
    }

    // per-wave softmax partial: all lanes hold this wave's total for n=nl
    ssum += __shfl_xor(ssum, 16);
    ssum += __shfl_xor(ssum, 32);
    if (lane < 16) sred[wv][lane] = ssum;
#pragma unroll
    for (int r = 0; r < 4; ++r) {
        yred[wv][q * 4 + r][nl]      = y0[r];
        yred[wv][16 + q * 4 + r][nl] = y1[r];
        yred[wv][32 + q * 4 + r][nl] = y2[r];
    }
    __syncthreads();

    // cross-wave reduce + divide + write yfin (40 rows x 16 n per WG)
    for (int v = t; v < 768; v += 256) {
        int c = v >> 4, n = v & 15;
        if (c < 40) {
            float s  = (yred[0][c][n] + yred[1][c][n])
                     + (yred[2][c][n] + yred[3][c][n]);
            float ss = (sred[0][n] + sred[1][n]) + (sred[2][n] + sred[3][n]);
            yfin[c * 4096 + n0 + n] = s / ss;
        }
    }
}

// ---------------- wz proj + BatchNorm + slow-mult + upsample -------------
__device__ __forceinline__ void taps_up(int i, int* j0, int* j1, float* w0, float* w1) {
    if (i == 0)        { *j0 = 0;        *j1 = 0;          *w0 = 0.f;   *w1 = 1.f;   }
    else if (i == 63)  { *j0 = 31;       *j1 = 31;         *w0 = 1.f;   *w1 = 0.f;   }
    else if (i & 1)    { *j0 = i >> 1;   *j1 = (i>>1) + 1; *w0 = 0.75f; *w1 = 0.25f; }
    else               { *j0 = (i>>1)-1; *j1 = i >> 1;     *w0 = 0.25f; *w1 = 0.75f; }
}

__global__ __launch_bounds__(256) void k_bn_up(
        const float* __restrict__ yfin, const float* __restrict__ wzw,
        const float* __restrict__ wzb, const float* __restrict__ bng,
        const float* __restrict__ bnb, const float* __restrict__ xs,
        float* __restrict__ out) {
    __shared__ float4 wrow4[1024];   // 16 KB
    __shared__ float sred[8];
    int ch = blockIdx.x;
    int t = threadIdx.x;
    float w[40];
#pragma unroll
    for (int o = 0; o < 40; ++o) w[o] = wzw[ch * 40 + o];
    float bias = wzb[ch];
    float s1 = 0.f, s2 = 0.f;
#pragma unroll 1
    for (int k = 0; k < 4; ++k) {
        int i = k * 256 + t;
        float4 yv[40];
#pragma unroll
        for (int o = 0; o < 40; ++o)
            yv[o] = *(const float4*)(yfin + o * 4096 + i * 4);
        float4 a = make_float4(bias, bias, bias, bias);
#pragma unroll
        for (int o = 0; o < 40; ++o) {
            a.x += w[o]*yv[o].x; a.y += w[o]*yv[o].y;
            a.z += w[o]*yv[o].z; a.w += w[o]*yv[o].w;
        }
        wrow4[i] = a;
        s1 += a.x + a.y + a.z + a.w;
        s2 += a.x*a.x + a.y*a.y + a.z*a.z + a.w*a.w;
    }
#pragma unroll
    for (int off = 32; off > 0; off >>= 1) {
        s1 += __shfl_down(s1, off);
        s2 += __shfl_down(s2, off);
    }
    int wid = t >> 6;
    if ((t & 63) == 0) { sred[wid] = s1; sred[4 + wid] = s2; }
    __syncthreads();
    float mean = (sred[0] + sred[1] + sred[2] + sred[3]) * (1.f / 4096.f);
    float var  = (sred[4] + sred[5] + sred[6] + sred[7]) * (1.f / 4096.f) - mean * mean;
    float inv = rsqrtf(var + 1e-5f);
    float sc = bng[ch] * inv;
    float sh = bnb[ch] - mean * sc;
#pragma unroll
    for (int k = 0; k < 4; ++k) {
        int i = k * 256 + t;
        float4 a = wrow4[i];
        float4 xv = *(const float4*)(xs + ch * 4096 + i * 4);
        a.x = (a.x*sc + sh)*xv.x; a.y = (a.y*sc + sh)*xv.y;
        a.z = (a.z*sc + sh)*xv.z; a.w = (a.w*sc + sh)*xv.w;
        wrow4[i] = a;
    }
    __syncthreads();
    const float* zs = (const float*)wrow4;
    int chbase = ch << 14;
#pragma unroll 4
    for (int k = 0; k < 64; ++k) {
        int p = k * 256 + t;          // 0..16383
        int tt = p >> 12, yy = (p >> 6) & 63, xx = p & 63;
        int jy0, jy1, jx0, jx1; float wy0, wy1, wx0, wx1;
        taps_up(yy, &jy0, &jy1, &wy0, &wy1);
        taps_up(xx, &jx0, &jx1, &wx0, &wx1);
        const float* pl = zs + tt * 1024;
        float r0 = wx0*pl[jy0*32 + jx0] + wx1*pl[jy0*32 + jx1];
        float r1 = wx0*pl[jy1*32 + jx0] + wx1*pl[jy1*32 + jx1];
        out[chbase + p] = wy0*r0 + wy1*r1;
    }
}

extern "C" void kernel_launch(void* const* d_in, const int* in_sizes, int n_in,
                              void* d_out, int out_size, void* d_ws, size_t ws_size,
                              hipStream_t stream) {
    const float* fast = (const float*)d_in[0];
    const float* slow = (const float*)d_in[1];
    const float* g_w  = (const float*)d_in[2];
    const float* g_b  = (const float*)d_in[3];
    const float* th_w = (const float*)d_in[4];
    const float* th_b = (const float*)d_in[5];
    const float* ph_w = (const float*)d_in[6];
    const float* ph_b = (const float*)d_in[7];
    const float* wz_w = (const float*)d_in[8];
    const float* wz_b = (const float*)d_in[9];
    const float* bn_g = (const float*)d_in[10];
    const float* bn_b = (const float*)d_in[11];
    float* out = (float*)d_out;
    float* ws  = (float*)d_ws;

    float* xf = ws;
    float* xs = ws + 327680;
    unsigned short* thetaP = (unsigned short*)(ws + 655360);
    unsigned short* phiP   = (unsigned short*)(ws + 786432);
    unsigned short* gxP    = (unsigned short*)(ws + 917504);
    float* yfin  = ws + 1015808;

    k_down<<<2560, 256, 0, stream>>>(fast, slow, xf, xs);
    k_proj<<<dim3(16, 20), 256, 0, stream>>>(xf, g_w, g_b, th_w, th_b, ph_w, ph_b,
                                             gxP, thetaP, phiP);
    k_attn<<<256, 256, 0, stream>>>(thetaP, phiP, gxP, yfin);
    k_bn_up<<<80, 256, 0, stream>>>(yfin, wz_w, wz_b, bn_g, bn_b, xs, out);
}